// Round 2
// baseline (505.921 us; speedup 1.0000x reference)
//
#include <hip/hip_runtime.h>

#define N_NODES 100000
#define D_FEAT  128
#define N_EDGES 1600000
#define EPSBN   1e-5f
#define SLOPE   0.01f

#define SCAN_NB 98           // 98 * 1024 = 100352 >= N_NODES

typedef __attribute__((ext_vector_type(8))) short bf16x8;
typedef __attribute__((ext_vector_type(4))) float f32x4;
typedef unsigned short u16;
typedef unsigned int   u32;

__device__ __forceinline__ u16 f2bf(float f) {
    u32 x = __float_as_uint(f);
    u32 r = (x + 0x7fffu + ((x >> 16) & 1u)) >> 16;
    return (u16)r;
}
__device__ __forceinline__ float bf_lo(u32 w) { return __uint_as_float(w << 16); }
__device__ __forceinline__ float bf_hi(u32 w) { return __uint_as_float(w & 0xffff0000u); }

// ---------------- setup ----------------

// zero BN-stat scratch, the dedicated zero-row of Hb (row N_NODES), and deg[].
__global__ void k_init(float* stats, u32* zrow, int* deg) {
    int i = blockIdx.x * 256 + threadIdx.x;
    if (i < 1024) stats[i] = 0.f;
    if (i < 64) zrow[i] = 0u;
    for (int k = i; k < N_NODES; k += gridDim.x * 256) deg[k] = 0;
}

// degree count via global atomics (avg 16 per counter -> low contention)
__global__ __launch_bounds__(256) void k_deg(const int* __restrict__ dst,
                                             int* __restrict__ deg) {
    int i = blockIdx.x * 256 + threadIdx.x;   // 6250 * 256 = 1.6M exact
    atomicAdd(&deg[dst[i]], 1);
}

// level-1 scan of padded row sizes c4 = (deg+4)&~3 (edges + self, pad to 4)
__global__ __launch_bounds__(1024) void k_scan1(const int* __restrict__ deg,
                                                int* __restrict__ rowrel,
                                                int* __restrict__ btot) {
    __shared__ int sc[1024];
    int t = threadIdx.x, node = blockIdx.x * 1024 + t;
    int c4 = (node < N_NODES) ? ((deg[node] + 4) & ~3) : 0;
    sc[t] = c4;
    __syncthreads();
    for (int off = 1; off < 1024; off <<= 1) {
        int add = (t >= off) ? sc[t - off] : 0;
        __syncthreads();
        sc[t] += add;
        __syncthreads();
    }
    rowrel[node] = sc[t] - c4;
    if (t == 1023) btot[blockIdx.x] = sc[1023];
}

// level-2 scan of the 98 block totals
__global__ __launch_bounds__(128) void k_scan2(const int* __restrict__ btot,
                                               int* __restrict__ bbase) {
    __shared__ int sc[128];
    int t = threadIdx.x;
    int v = (t < SCAN_NB) ? btot[t] : 0;
    sc[t] = v;
    __syncthreads();
    for (int off = 1; off < 128; off <<= 1) {
        int add = (t >= off) ? sc[t - off] : 0;
        __syncthreads();
        sc[t] += add;
        __syncthreads();
    }
    bbase[t] = sc[t] - v;
}

// per-node: meta {row_start_in_int4, rounds, bits(dinv)}, dinv, placement cursor,
// self slot (csr[excl+c] = node) and zero-row pads.
__global__ __launch_bounds__(1024) void k_finish(const int* __restrict__ deg,
                                                 const int* __restrict__ rowrel,
                                                 const int* __restrict__ bbase,
                                                 int4* __restrict__ meta,
                                                 float* __restrict__ dinv,
                                                 int* __restrict__ csr,
                                                 int* __restrict__ cur) {
    int t = threadIdx.x, node = blockIdx.x * 1024 + t;
    if (node >= N_NODES) return;
    int c  = deg[node];
    int c4 = (c + 4) & ~3;
    int excl = bbase[blockIdx.x] + rowrel[node];
    float di = rsqrtf((float)(c + 1));
    dinv[node] = di;
    int4 m; m.x = excl >> 2; m.y = c4 >> 2; m.z = __float_as_int(di); m.w = 0;
    meta[node] = m;
    cur[node] = excl;
    csr[excl + c] = node;                          // self (Hb already *dinv)
    for (int k = c + 1; k < c4; ++k) csr[excl + k] = N_NODES;   // zero-row pads
}

// place edges: slot = atomicAdd(cur[dst]), csr[slot] = src
__global__ __launch_bounds__(256) void k_place(const int* __restrict__ src,
                                               const int* __restrict__ dst,
                                               int* __restrict__ cur,
                                               int* __restrict__ csr) {
    int i = blockIdx.x * 256 + threadIdx.x;   // 6250 * 256 = 1.6M exact
    int d = dst[i];
    int slot = atomicAdd(&cur[d], 1);
    csr[slot] = src[i];
}

// Pre-swizzle W (128x128 f32, row-major W[k][n]) into MFMA B-fragment order (bf16):
// frag t = (kc*8+nt)*64+lane holds 8 bf16: W[kc*32+(lane>>4)*8+j][nt*16+(lane&15)]
__global__ void k_swz(const float* __restrict__ W, u16* __restrict__ Wz) {
    int t = blockIdx.x * 256 + threadIdx.x;  // 0..2047
    int lane = t & 63, frag = t >> 6;
    int nt = frag & 7, kc = frag >> 3;
    int n  = nt * 16 + (lane & 15);
    int kb = kc * 32 + (lane >> 4) * 8;
    u16 tmp[8];
#pragma unroll
    for (int j = 0; j < 8; ++j) tmp[j] = f2bf(W[(kb + j) * 128 + n]);
#pragma unroll
    for (int j = 0; j < 8; ++j) Wz[t * 8 + j] = tmp[j];
}

// ---- GEMM: Hb[M x 128](bf16) = (act(A) @ W) * dinv[row]
//   ABF16: A is packed bf16 (u32 pairs, 64/row); else f32.
//   FUSE:  act = leaky(A*scale+shift)

template <bool FUSE, bool ABF16>
__global__ __launch_bounds__(256) void k_gemm(const void* __restrict__ Ap,
                                              const u16* __restrict__ Wz,
                                              const float* __restrict__ scale,
                                              const float* __restrict__ shift,
                                              const float* __restrict__ dinv,
                                              u16* __restrict__ Hb, int M) {
    __shared__ u16 wl[16384];  // 32 KB
    __shared__ float sLds[128], hLds[128];
    int tid = threadIdx.x;
    {
        const uint4* s4 = (const uint4*)Wz;
        uint4* d4 = (uint4*)wl;
        for (int i = tid; i < 2048; i += 256) d4[i] = s4[i];
    }
    if (FUSE && tid < 128) { sLds[tid] = scale[tid]; hLds[tid] = shift[tid]; }
    __syncthreads();
    int wave = tid >> 6, lane = tid & 63;
    long m0 = ((long)blockIdx.x * 4 + wave) * 16;
    if (m0 >= M) return;
    int mr = lane & 15, quad = lane >> 4;
    f32x4 acc[8] = {};
#pragma unroll
    for (int kc = 0; kc < 4; ++kc) {
        float av[8];
        if (ABF16) {
            const u32* arow = (const u32*)Ap + (size_t)(m0 + mr) * 64;
            uint4 aw = ((const uint4*)arow)[kc * 4 + quad];
            av[0] = bf_lo(aw.x); av[1] = bf_hi(aw.x);
            av[2] = bf_lo(aw.y); av[3] = bf_hi(aw.y);
            av[4] = bf_lo(aw.z); av[5] = bf_hi(aw.z);
            av[6] = bf_lo(aw.w); av[7] = bf_hi(aw.w);
        } else {
            const float* arow = (const float*)Ap + (size_t)(m0 + mr) * 128 + quad * 8;
            float4 a0 = *(const float4*)(arow + kc * 32);
            float4 a1 = *(const float4*)(arow + kc * 32 + 4);
            av[0] = a0.x; av[1] = a0.y; av[2] = a0.z; av[3] = a0.w;
            av[4] = a1.x; av[5] = a1.y; av[6] = a1.z; av[7] = a1.w;
        }
        if (FUSE) {
            int c = kc * 32 + quad * 8;
#pragma unroll
            for (int j = 0; j < 8; ++j) {
                float v = fmaf(av[j], sLds[c + j], hLds[c + j]);
                av[j] = v > 0.f ? v : v * SLOPE;
            }
        }
        bf16x8 af;
#pragma unroll
        for (int j = 0; j < 8; ++j) af[j] = (short)f2bf(av[j]);
        const u16* wb = wl + (kc * 4096 + lane * 8);  // fragment (kc,nt) at (kc*8+nt)*512
#pragma unroll
        for (int nt = 0; nt < 8; ++nt) {
            bf16x8 bf = *(const bf16x8*)(wb + nt * 512);
            acc[nt] = __builtin_amdgcn_mfma_f32_16x16x32_bf16(af, bf, acc[nt], 0, 0, 0);
        }
    }
    // C/D layout: col = lane&15, row = quad*4 + r ; scale row by dinv, store bf16
    float dr[4];
#pragma unroll
    for (int r = 0; r < 4; ++r) dr[r] = dinv[m0 + quad * 4 + r];
    u16* hb = Hb + (size_t)m0 * 128 + (lane & 15);
#pragma unroll
    for (int nt = 0; nt < 8; ++nt)
#pragma unroll
        for (int r = 0; r < 4; ++r)
            hb[(size_t)(quad * 4 + r) * 128 + nt * 16] = f2bf(acc[nt][r] * dr[r]);
}

// ---------------- aggregation ----------------
// One wave per node, 4 groups of 16 lanes. Padded CSR rows (multiple of 4,
// self folded in, zero-row pads): group g handles int4 slots r = g, g+4, ...
// Per round: one broadcast int4 index load + 4 row gathers + adds. No shfl,
// no tail masking, no weighted path.
// AGGb[d] = bf16( dinv[d] * sum_slots Hb[slot] )

__device__ __forceinline__ void add8(float* acc, uint4 w) {
    acc[0] += bf_lo(w.x); acc[1] += bf_hi(w.x);
    acc[2] += bf_lo(w.y); acc[3] += bf_hi(w.y);
    acc[4] += bf_lo(w.z); acc[5] += bf_hi(w.z);
    acc[6] += bf_lo(w.w); acc[7] += bf_hi(w.w);
}

__global__ __launch_bounds__(256) void k_agg(const uint4* __restrict__ Hb4,
                                             const int4* __restrict__ meta,
                                             const int4* __restrict__ csr4,
                                             u32* __restrict__ AGGb) {
    int wave = threadIdx.x >> 6, lane = threadIdx.x & 63;
    int node = blockIdx.x * 4 + wave;  // 25000*4 = 100000 exact
    int g = lane >> 4, f = lane & 15;
    int4 m = meta[node];               // wave-uniform 16B broadcast
    int s4 = m.x, rn = m.y;
    float di = __int_as_float(m.z);
    float acc[8] = {0.f, 0.f, 0.f, 0.f, 0.f, 0.f, 0.f, 0.f};
    for (int r = g; r < rn; r += 4) {
        int4 idx = csr4[s4 + r];       // 16 lanes same addr; 4 groups = 64B line
        uint4 a0 = Hb4[((size_t)idx.x << 4) + f];
        uint4 a1 = Hb4[((size_t)idx.y << 4) + f];
        uint4 a2 = Hb4[((size_t)idx.z << 4) + f];
        uint4 a3 = Hb4[((size_t)idx.w << 4) + f];
        add8(acc, a0); add8(acc, a1); add8(acc, a2); add8(acc, a3);
    }
#pragma unroll
    for (int i = 0; i < 8; ++i) {
        acc[i] += __shfl_xor(acc[i], 16);
        acc[i] += __shfl_xor(acc[i], 32);
    }
#pragma unroll
    for (int i = 0; i < 8; ++i) acc[i] *= di;
    if (g == 0) {                      // all groups hold the full sum; one writes
        u32 p0 = (u32)f2bf(acc[0]) | ((u32)f2bf(acc[1]) << 16);
        u32 p1 = (u32)f2bf(acc[2]) | ((u32)f2bf(acc[3]) << 16);
        u32 p2 = (u32)f2bf(acc[4]) | ((u32)f2bf(acc[5]) << 16);
        u32 p3 = (u32)f2bf(acc[6]) | ((u32)f2bf(acc[7]) << 16);
        uint4 o; o.x = p0; o.y = p1; o.z = p2; o.w = p3;
        ((uint4*)(AGGb + (size_t)node * 64))[f] = o;
    }
}

// ---------------- batch norm (bf16 AGG input) ----------------

__global__ void k_bnstats(const u32* __restrict__ AGGb, float* __restrict__ sums,
                          float* __restrict__ sumsq) {
    __shared__ float red[256];
    int col  = threadIdx.x & 127;
    int half = threadIdx.x >> 7;
    int odd  = col & 1, c2 = col >> 1;
    long r0 = (long)blockIdx.x * 200 + half;  // 500 blocks * 200 rows = 100000
    float s = 0.f, s2 = 0.f;
    for (int k = 0; k < 200; k += 2) {
        u32 w = AGGb[(r0 + k) * 64 + c2];
        float v = odd ? bf_hi(w) : bf_lo(w);
        s += v;
        s2 = fmaf(v, v, s2);
    }
    red[threadIdx.x] = s; __syncthreads();
    if (threadIdx.x < 128) atomicAdd(&sums[col], red[threadIdx.x] + red[threadIdx.x + 128]);
    __syncthreads();
    red[threadIdx.x] = s2; __syncthreads();
    if (threadIdx.x < 128) atomicAdd(&sumsq[col], red[threadIdx.x] + red[threadIdx.x + 128]);
}

__global__ void k_bnfin(const float* __restrict__ sums, const float* __restrict__ sumsq,
                        const float* __restrict__ g, const float* __restrict__ be,
                        float* __restrict__ scale, float* __restrict__ shift) {
    int c = threadIdx.x;  // 128 threads
    float mean = sums[c] * (1.f / N_NODES);
    float var  = sumsq[c] * (1.f / N_NODES) - mean * mean;
    float rstd = rsqrtf(var + EPSBN);
    float gg = g[c] * rstd;
    scale[c] = gg;
    shift[c] = be[c] - mean * gg;
}

// out = leaky(agg*scale + shift + x), f32 out; AGG is bf16-packed
__global__ void k_ew2(const u32* __restrict__ AGGb, const float* __restrict__ scale,
                      const float* __restrict__ shift, const float* __restrict__ x,
                      float* __restrict__ out) {
    long i = (long)blockIdx.x * 256 + threadIdx.x;  // one u32 / float2 per thread
    int c2 = (int)(i & 63);
    u32 w = AGGb[i];
    float2 sc = ((const float2*)scale)[c2];
    float2 sh = ((const float2*)shift)[c2];
    float2 xv = ((const float2*)x)[i];
    float2 o;
    o.x = fmaf(bf_lo(w), sc.x, sh.x) + xv.x; o.x = o.x > 0.f ? o.x : o.x * SLOPE;
    o.y = fmaf(bf_hi(w), sc.y, sh.y) + xv.y; o.y = o.y > 0.f ? o.y : o.y * SLOPE;
    ((float2*)out)[i] = o;
}

// ---------------- launch ----------------

extern "C" void kernel_launch(void* const* d_in, const int* in_sizes, int n_in,
                              void* d_out, int out_size, void* d_ws, size_t ws_size,
                              hipStream_t stream) {
    const float* x   = (const float*)d_in[0];
    const int*   ei  = (const int*)d_in[1];
    const float* W1  = (const float*)d_in[2];
    const float* g1  = (const float*)d_in[4];
    const float* be1 = (const float*)d_in[5];
    const float* W2  = (const float*)d_in[6];
    const float* g2  = (const float*)d_in[8];
    const float* be2 = (const float*)d_in[9];
    const int* src = ei;
    const int* dst = ei + N_EDGES;

    float* out = (float*)d_out;
    u16*   Hb  = (u16*)d_out;  // bf16 H (rows 0..N_NODES incl zero-row) lives in d_out

    char* p = (char*)d_ws;
    u32*   aggb    = (u32*)p;   p += (size_t)N_NODES * 64 * 4;   // 25.6 MB bf16 AGG
    int*   csr_src = (int*)p;   p += (size_t)2200000 * 4;        // 8.8 MB padded CSR
    int*   deg     = (int*)p;   p += (size_t)100352 * 4;
    int*   cur     = (int*)p;   p += (size_t)100352 * 4;
    int*   rowrel  = (int*)p;   p += (size_t)100352 * 4;
    int*   btot    = (int*)p;   p += 128 * 4;
    int*   bbase   = (int*)p;   p += 128 * 4;
    int4*  meta    = (int4*)p;  p += (size_t)100352 * 16;        // 1.6 MB
    float* dinv    = (float*)p; p += (size_t)100352 * 4;
    float* stats   = (float*)p; p += 1024 * 4;
    u16*   wz1     = (u16*)p;   p += 16384 * 2;
    u16*   wz2     = (u16*)p;   p += 16384 * 2;

    float* sums1 = stats,       *sq1 = stats + 128, *scale1 = stats + 256, *shift1 = stats + 384;
    float* sums2 = stats + 512, *sq2 = stats + 640, *scale2 = stats + 768, *shift2 = stats + 896;

    // graph setup: direct CSR build — deg atomics -> 2-level scan -> meta/self/pads -> place
    k_init<<<391, 256, 0, stream>>>(stats, (u32*)Hb + (size_t)N_NODES * 64, deg);
    k_deg<<<6250, 256, 0, stream>>>(dst, deg);
    k_scan1<<<SCAN_NB, 1024, 0, stream>>>(deg, rowrel, btot);
    k_scan2<<<1, 128, 0, stream>>>(btot, bbase);
    k_finish<<<SCAN_NB, 1024, 0, stream>>>(deg, rowrel, bbase, meta, dinv, csr_src, cur);
    k_place<<<6250, 256, 0, stream>>>(src, dst, cur, csr_src);
    k_swz<<<8, 256, 0, stream>>>(W1, wz1);
    k_swz<<<8, 256, 0, stream>>>(W2, wz2);

    // layer 1:  Hb1 = (x@W1)*dinv -> d_out (bf16),  AGG1(bf16) -> aggb
    k_gemm<false, false><<<1563, 256, 0, stream>>>(x, wz1, nullptr, nullptr, dinv, Hb, N_NODES);
    k_agg<<<25000, 256, 0, stream>>>((const uint4*)Hb, meta, (const int4*)csr_src, aggb);
    k_bnstats<<<500, 256, 0, stream>>>(aggb, sums1, sq1);
    k_bnfin<<<1, 128, 0, stream>>>(sums1, sq1, g1, be1, scale1, shift1);

    // layer 2:  Hb2 = (leaky(BN1(AGG1))@W2)*dinv -> d_out;  AGG2(bf16) -> aggb
    k_gemm<true, true><<<1563, 256, 0, stream>>>(aggb, wz2, scale1, shift1, dinv, Hb, N_NODES);
    k_agg<<<25000, 256, 0, stream>>>((const uint4*)Hb, meta, (const int4*)csr_src, aggb);
    k_bnstats<<<500, 256, 0, stream>>>(aggb, sums2, sq2);
    k_bnfin<<<1, 128, 0, stream>>>(sums2, sq2, g2, be2, scale2, shift2);
    k_ew2<<<25000, 256, 0, stream>>>(aggb, scale2, shift2, x, out);
}

// Round 3
// 373.146 us; speedup vs baseline: 1.3558x; 1.3558x over previous
//
#include <hip/hip_runtime.h>

#define N_NODES 100000
#define D_FEAT  128
#define N_EDGES 1600000
#define EPSBN   1e-5f
#define SLOPE   0.01f

#define NBUCK   782          // ceil(100000 / 128) dst-buckets (128 nodes each)
#define PBLK    256          // partition blocks
#define CHUNK   6250         // edges per partition block (256*6250 = 1.6M exact)
#define PADMARG 640          // per-bucket extra csr capacity: 128 nodes * (+self +3 pad) + align

typedef __attribute__((ext_vector_type(8))) short bf16x8;
typedef __attribute__((ext_vector_type(4))) float f32x4;
typedef unsigned short u16;
typedef unsigned int   u32;

__device__ __forceinline__ u16 f2bf(float f) {
    u32 x = __float_as_uint(f);
    u32 r = (x + 0x7fffu + ((x >> 16) & 1u)) >> 16;
    return (u16)r;
}
__device__ __forceinline__ float bf_lo(u32 w) { return __uint_as_float(w << 16); }
__device__ __forceinline__ float bf_hi(u32 w) { return __uint_as_float(w & 0xffff0000u); }

// ---------------- setup ----------------

// zero the BN-stat scratch AND the dedicated zero-row of Hb (row N_NODES).
__global__ void k_init(float* stats, u32* zrow) {
    int i = blockIdx.x * 256 + threadIdx.x;
    if (i < 1024) stats[i] = 0.f;
    if (blockIdx.x == 0 && threadIdx.x < 64) zrow[threadIdx.x] = 0u;
}

// P1: per-(chunk-block, bucket) histogram in LDS. hist[blk*NBUCK + b].
__global__ __launch_bounds__(256) void k_hist(const int* __restrict__ dst,
                                              int* __restrict__ hist) {
    __shared__ int h[NBUCK];
    int tid = threadIdx.x, blk = blockIdx.x;
    for (int i = tid; i < NBUCK; i += 256) h[i] = 0;
    __syncthreads();
    int e0 = blk * CHUNK;
    for (int e = e0 + tid; e < e0 + CHUNK; e += 256)
        atomicAdd(&h[dst[e] >> 7], 1);
    __syncthreads();
    for (int i = tid; i < NBUCK; i += 256) hist[blk * NBUCK + i] = h[i];
}

// P2a: per-bucket exclusive scan over the 256 chunk-blocks (relative offsets);
// bucket total -> tot[b].
__global__ __launch_bounds__(256) void k_colscan(int* __restrict__ hist,
                                                 int* __restrict__ tot) {
    __shared__ int sc[256];
    int t = threadIdx.x, b = blockIdx.x;   // b in [0, NBUCK)
    int c = hist[t * NBUCK + b];
    sc[t] = c;
    __syncthreads();
    for (int off = 1; off < 256; off <<= 1) {
        int add = (t >= off) ? sc[t - off] : 0;
        __syncthreads();
        sc[t] += add;
        __syncthreads();
    }
    hist[t * NBUCK + b] = sc[t] - c;       // relative offset within bucket
    if (t == 255) tot[b] = sc[255];
}

// P2b: exclusive scan of the 782 bucket totals -> bucket_base[0..NBUCK].
__global__ __launch_bounds__(1024) void k_bscan(const int* __restrict__ tot,
                                                int* __restrict__ bucket_base) {
    __shared__ int sc[1024];
    int t = threadIdx.x;
    int v = (t < NBUCK) ? tot[t] : 0;
    sc[t] = v;
    __syncthreads();
    for (int off = 1; off < 1024; off <<= 1) {
        int add = (t >= off) ? sc[t - off] : 0;
        __syncthreads();
        sc[t] += add;
        __syncthreads();
    }
    if (t < NBUCK) bucket_base[t] = sc[t] - v;
    if (t == 0) bucket_base[NBUCK] = N_EDGES;
}

// P3: partition edges into bucket-contiguous regions of tmp, packed 4B:
//   pk = src | (dst&127) << 20     (src < 2^17)
__global__ __launch_bounds__(256) void k_part(const int* __restrict__ src,
                                              const int* __restrict__ dst,
                                              const int* __restrict__ hist,
                                              const int* __restrict__ bucket_base,
                                              u32* __restrict__ tmp) {
    __shared__ int cur[NBUCK];
    int tid = threadIdx.x, blk = blockIdx.x;
    for (int i = tid; i < NBUCK; i += 256)
        cur[i] = bucket_base[i] + hist[blk * NBUCK + i];
    __syncthreads();
    int e0 = blk * CHUNK;
    for (int e = e0 + tid; e < e0 + CHUNK; e += 256) {
        int s = src[e], d = dst[e];
        int slot = atomicAdd(&cur[d >> 7], 1);
        tmp[slot] = (u32)s | ((u32)(d & 127) << 20);
    }
}

// P4: one block per bucket. Count 128 node degrees in LDS, LDS-scan over
// PADDED counts (self + pad-to-4) -> padded CSR rows:
//   row = [edges..., self, N_NODES-pads...]   (length multiple of 4, int4-aligned)
// meta[node] = { row_start_in_int4, rounds, bits(dinv), 0 }
__global__ __launch_bounds__(256) void k_bucket(const u32* __restrict__ tmp,
                                                const int* __restrict__ bucket_base,
                                                int4* __restrict__ meta,
                                                float* __restrict__ dinv,
                                                int* __restrict__ csr_src) {
    __shared__ int lcnt[128];
    __shared__ int sc[128];
    __shared__ int lcur[128];
    int tid = threadIdx.x, b = blockIdx.x;
    int lo = bucket_base[b], hi = bucket_base[b + 1];
    int pbase = (lo & ~3) + b * PADMARG;        // int4-aligned padded region base
    if (tid < 128) lcnt[tid] = 0;
    __syncthreads();
    for (int e = lo + tid; e < hi; e += 256)
        atomicAdd(&lcnt[tmp[e] >> 20], 1);
    __syncthreads();
    int c  = (tid < 128) ? lcnt[tid] : 0;
    int c4 = (c + 4) & ~3;                      // edges + self, rounded up to 4
    if (tid < 128) sc[tid] = c4;
    __syncthreads();
    for (int off = 1; off < 128; off <<= 1) {
        int add = (tid < 128 && tid >= off) ? sc[tid - off] : 0;
        __syncthreads();
        if (tid < 128) sc[tid] += add;
        __syncthreads();
    }
    if (tid < 128) {
        int node = (b << 7) + tid;
        int excl = pbase + sc[tid] - c4;
        lcur[tid] = excl;
        if (node < N_NODES) {
            float di = rsqrtf((float)(c + 1));
            dinv[node] = di;
            int4 m; m.x = excl >> 2; m.y = c4 >> 2; m.z = __float_as_int(di); m.w = 0;
            meta[node] = m;
            csr_src[excl + c] = node;           // self contribution (Hb already *dinv)
            for (int k = c + 1; k < c4; ++k) csr_src[excl + k] = N_NODES;  // zero row
        }
    }
    __syncthreads();
    for (int e = lo + tid; e < hi; e += 256) {
        u32 pk = tmp[e];
        int slot = atomicAdd(&lcur[pk >> 20], 1);
        csr_src[slot] = (int)(pk & 0xFFFFFu);
    }
}

// Pre-swizzle W (128x128 f32, row-major W[k][n]) into MFMA B-fragment order (bf16):
// frag t = (kc*8+nt)*64+lane holds 8 bf16: W[kc*32+(lane>>4)*8+j][nt*16+(lane&15)]
__global__ void k_swz(const float* __restrict__ W, u16* __restrict__ Wz) {
    int t = blockIdx.x * 256 + threadIdx.x;  // 0..2047
    int lane = t & 63, frag = t >> 6;
    int nt = frag & 7, kc = frag >> 3;
    int n  = nt * 16 + (lane & 15);
    int kb = kc * 32 + (lane >> 4) * 8;
    u16 tmp[8];
#pragma unroll
    for (int j = 0; j < 8; ++j) tmp[j] = f2bf(W[(kb + j) * 128 + n]);
#pragma unroll
    for (int j = 0; j < 8; ++j) Wz[t * 8 + j] = tmp[j];
}

// ---- GEMM: Hb[M x 128](bf16) = (act(A) @ W) * dinv[row]
//   ABF16: A is packed bf16 (u32 pairs, 64/row); else f32.
//   FUSE:  act = leaky(A*scale+shift), scale/shift computed from BN sums in prologue

template <bool FUSE, bool ABF16>
__global__ __launch_bounds__(256) void k_gemm(const void* __restrict__ Ap,
                                              const u16* __restrict__ Wz,
                                              const float* __restrict__ sums,
                                              const float* __restrict__ sumsq,
                                              const float* __restrict__ gam,
                                              const float* __restrict__ bet,
                                              const float* __restrict__ dinv,
                                              u16* __restrict__ Hb, int M) {
    __shared__ u16 wl[16384];  // 32 KB
    __shared__ float sLds[128], hLds[128];
    int tid = threadIdx.x;
    {
        const uint4* s4 = (const uint4*)Wz;
        uint4* d4 = (uint4*)wl;
        for (int i = tid; i < 2048; i += 256) d4[i] = s4[i];
    }
    if (FUSE && tid < 128) {
        float mean = sums[tid] * (1.f / N_NODES);
        float var  = sumsq[tid] * (1.f / N_NODES) - mean * mean;
        float rstd = rsqrtf(var + EPSBN);
        float sc = gam[tid] * rstd;
        sLds[tid] = sc;
        hLds[tid] = bet[tid] - mean * sc;
    }
    __syncthreads();
    int wave = tid >> 6, lane = tid & 63;
    long m0 = ((long)blockIdx.x * 4 + wave) * 16;
    if (m0 >= M) return;
    int mr = lane & 15, quad = lane >> 4;
    f32x4 acc[8] = {};
#pragma unroll
    for (int kc = 0; kc < 4; ++kc) {
        float av[8];
        if (ABF16) {
            const u32* arow = (const u32*)Ap + (size_t)(m0 + mr) * 64;
            uint4 aw = ((const uint4*)arow)[kc * 4 + quad];
            av[0] = bf_lo(aw.x); av[1] = bf_hi(aw.x);
            av[2] = bf_lo(aw.y); av[3] = bf_hi(aw.y);
            av[4] = bf_lo(aw.z); av[5] = bf_hi(aw.z);
            av[6] = bf_lo(aw.w); av[7] = bf_hi(aw.w);
        } else {
            const float* arow = (const float*)Ap + (size_t)(m0 + mr) * 128 + quad * 8;
            float4 a0 = *(const float4*)(arow + kc * 32);
            float4 a1 = *(const float4*)(arow + kc * 32 + 4);
            av[0] = a0.x; av[1] = a0.y; av[2] = a0.z; av[3] = a0.w;
            av[4] = a1.x; av[5] = a1.y; av[6] = a1.z; av[7] = a1.w;
        }
        if (FUSE) {
            int c = kc * 32 + quad * 8;
#pragma unroll
            for (int j = 0; j < 8; ++j) {
                float v = fmaf(av[j], sLds[c + j], hLds[c + j]);
                av[j] = v > 0.f ? v : v * SLOPE;
            }
        }
        bf16x8 af;
#pragma unroll
        for (int j = 0; j < 8; ++j) af[j] = (short)f2bf(av[j]);
        const u16* wb = wl + (kc * 4096 + lane * 8);  // fragment (kc,nt) at (kc*8+nt)*512
#pragma unroll
        for (int nt = 0; nt < 8; ++nt) {
            bf16x8 bf = *(const bf16x8*)(wb + nt * 512);
            acc[nt] = __builtin_amdgcn_mfma_f32_16x16x32_bf16(af, bf, acc[nt], 0, 0, 0);
        }
    }
    // C/D layout: col = lane&15, row = quad*4 + r ; scale row by dinv, store bf16
    float dr[4];
#pragma unroll
    for (int r = 0; r < 4; ++r) dr[r] = dinv[m0 + quad * 4 + r];
    u16* hb = Hb + (size_t)m0 * 128 + (lane & 15);
#pragma unroll
    for (int nt = 0; nt < 8; ++nt)
#pragma unroll
        for (int r = 0; r < 4; ++r)
            hb[(size_t)(quad * 4 + r) * 128 + nt * 16] = f2bf(acc[nt][r] * dr[r]);
}

// ---------------- aggregation ----------------
// One wave per node, 4 groups of 16 lanes. Padded CSR rows (multiple of 4,
// self folded in, zero-row pads): group g handles int4 slots r = g, g+4, ...
// Per round: one broadcast int4 index load + 4 row gathers + adds. No shfl,
// no tail masking, no weighted path.
// AGGb[d] = bf16( dinv[d] * sum_slots Hb[slot] )

__device__ __forceinline__ void add8(float* acc, uint4 w) {
    acc[0] += bf_lo(w.x); acc[1] += bf_hi(w.x);
    acc[2] += bf_lo(w.y); acc[3] += bf_hi(w.y);
    acc[4] += bf_lo(w.z); acc[5] += bf_hi(w.z);
    acc[6] += bf_lo(w.w); acc[7] += bf_hi(w.w);
}

__global__ __launch_bounds__(256) void k_agg(const uint4* __restrict__ Hb4,
                                             const int4* __restrict__ meta,
                                             const int4* __restrict__ csr4,
                                             u32* __restrict__ AGGb) {
    int wave = threadIdx.x >> 6, lane = threadIdx.x & 63;
    int node = blockIdx.x * 4 + wave;  // 25000*4 = 100000 exact
    int g = lane >> 4, f = lane & 15;
    int4 m = meta[node];               // wave-uniform 16B broadcast
    int s4 = m.x, rn = m.y;
    float di = __int_as_float(m.z);
    float acc[8] = {0.f, 0.f, 0.f, 0.f, 0.f, 0.f, 0.f, 0.f};
    for (int r = g; r < rn; r += 4) {
        int4 idx = csr4[s4 + r];       // 16 lanes same addr; 4 groups = 64B line
        uint4 a0 = Hb4[((size_t)idx.x << 4) + f];
        uint4 a1 = Hb4[((size_t)idx.y << 4) + f];
        uint4 a2 = Hb4[((size_t)idx.z << 4) + f];
        uint4 a3 = Hb4[((size_t)idx.w << 4) + f];
        add8(acc, a0); add8(acc, a1); add8(acc, a2); add8(acc, a3);
    }
#pragma unroll
    for (int i = 0; i < 8; ++i) {
        acc[i] += __shfl_xor(acc[i], 16);
        acc[i] += __shfl_xor(acc[i], 32);
    }
#pragma unroll
    for (int i = 0; i < 8; ++i) acc[i] *= di;
    if (g == 0) {                      // all groups hold the full sum; one writes
        u32 p0 = (u32)f2bf(acc[0]) | ((u32)f2bf(acc[1]) << 16);
        u32 p1 = (u32)f2bf(acc[2]) | ((u32)f2bf(acc[3]) << 16);
        u32 p2 = (u32)f2bf(acc[4]) | ((u32)f2bf(acc[5]) << 16);
        u32 p3 = (u32)f2bf(acc[6]) | ((u32)f2bf(acc[7]) << 16);
        uint4 o; o.x = p0; o.y = p1; o.z = p2; o.w = p3;
        ((uint4*)(AGGb + (size_t)node * 64))[f] = o;
    }
}

// ---------------- batch norm (bf16 AGG input) ----------------

__global__ void k_bnstats(const u32* __restrict__ AGGb, float* __restrict__ sums,
                          float* __restrict__ sumsq) {
    __shared__ float red[256];
    int col  = threadIdx.x & 127;
    int half = threadIdx.x >> 7;
    int odd  = col & 1, c2 = col >> 1;
    long r0 = (long)blockIdx.x * 200 + half;  // 500 blocks * 200 rows = 100000
    float s = 0.f, s2 = 0.f;
    for (int k = 0; k < 200; k += 2) {
        u32 w = AGGb[(r0 + k) * 64 + c2];
        float v = odd ? bf_hi(w) : bf_lo(w);
        s += v;
        s2 = fmaf(v, v, s2);
    }
    red[threadIdx.x] = s; __syncthreads();
    if (threadIdx.x < 128) atomicAdd(&sums[col], red[threadIdx.x] + red[threadIdx.x + 128]);
    __syncthreads();
    red[threadIdx.x] = s2; __syncthreads();
    if (threadIdx.x < 128) atomicAdd(&sumsq[col], red[threadIdx.x] + red[threadIdx.x + 128]);
}

// out = leaky(agg*scale + shift + x), f32 out; AGG bf16-packed, BN finalize inline.
// One thread = one uint4 of AGG (8 cols) + 2 float4 of x / out.
__global__ __launch_bounds__(256) void k_ew2(const uint4* __restrict__ AGGb4,
                                             const float* __restrict__ sums,
                                             const float* __restrict__ sumsq,
                                             const float* __restrict__ gam,
                                             const float* __restrict__ bet,
                                             const float4* __restrict__ x4,
                                             float4* __restrict__ out4) {
    __shared__ float sLds[128], hLds[128];
    int tid = threadIdx.x;
    if (tid < 128) {
        float mean = sums[tid] * (1.f / N_NODES);
        float var  = sumsq[tid] * (1.f / N_NODES) - mean * mean;
        float rstd = rsqrtf(var + EPSBN);
        float sc = gam[tid] * rstd;
        sLds[tid] = sc;
        hLds[tid] = bet[tid] - mean * sc;
    }
    __syncthreads();
    long i = (long)blockIdx.x * 256 + tid;   // uint4 index; 6250*256 = 1.6M exact
    int c8 = ((int)i & 15) * 8;
    uint4 w = AGGb4[i];
    float4 xa = x4[2 * i], xb = x4[2 * i + 1];
    float4 oa, ob;
    float v;
    v = fmaf(bf_lo(w.x), sLds[c8+0], hLds[c8+0]) + xa.x; oa.x = v > 0.f ? v : v * SLOPE;
    v = fmaf(bf_hi(w.x), sLds[c8+1], hLds[c8+1]) + xa.y; oa.y = v > 0.f ? v : v * SLOPE;
    v = fmaf(bf_lo(w.y), sLds[c8+2], hLds[c8+2]) + xa.z; oa.z = v > 0.f ? v : v * SLOPE;
    v = fmaf(bf_hi(w.y), sLds[c8+3], hLds[c8+3]) + xa.w; oa.w = v > 0.f ? v : v * SLOPE;
    v = fmaf(bf_lo(w.z), sLds[c8+4], hLds[c8+4]) + xb.x; ob.x = v > 0.f ? v : v * SLOPE;
    v = fmaf(bf_hi(w.z), sLds[c8+5], hLds[c8+5]) + xb.y; ob.y = v > 0.f ? v : v * SLOPE;
    v = fmaf(bf_lo(w.w), sLds[c8+6], hLds[c8+6]) + xb.z; ob.z = v > 0.f ? v : v * SLOPE;
    v = fmaf(bf_hi(w.w), sLds[c8+7], hLds[c8+7]) + xb.w; ob.w = v > 0.f ? v : v * SLOPE;
    out4[2 * i]     = oa;
    out4[2 * i + 1] = ob;
}

// ---------------- launch ----------------

extern "C" void kernel_launch(void* const* d_in, const int* in_sizes, int n_in,
                              void* d_out, int out_size, void* d_ws, size_t ws_size,
                              hipStream_t stream) {
    const float* x   = (const float*)d_in[0];
    const int*   ei  = (const int*)d_in[1];
    const float* W1  = (const float*)d_in[2];
    const float* g1  = (const float*)d_in[4];
    const float* be1 = (const float*)d_in[5];
    const float* W2  = (const float*)d_in[6];
    const float* g2  = (const float*)d_in[8];
    const float* be2 = (const float*)d_in[9];
    const int* src = ei;
    const int* dst = ei + N_EDGES;

    float* out = (float*)d_out;
    u16*   Hb  = (u16*)d_out;  // bf16 H (rows 0..N_NODES incl zero-row) lives in d_out

    char* p = (char*)d_ws;
    u32*   aggb    = (u32*)p;   p += (size_t)N_NODES * 64 * 4;   // 25.6 MB bf16 AGG
    u32*   tmp     = (u32*)p;   p += (size_t)N_EDGES * 4;        // 6.4 MB packed edges
    int*   csr_src = (int*)p;   p += (size_t)2200000 * 4;        // 8.8 MB padded CSR
    int*   hist    = (int*)p;   p += (size_t)PBLK * NBUCK * 4;   // 0.8 MB
    int*   tot     = (int*)p;   p += 1024 * 4;
    int*   bbase   = (int*)p;   p += 1024 * 4;
    int4*  meta    = (int4*)p;  p += (size_t)100096 * 16;        // 1.6 MB
    float* dinv    = (float*)p; p += (size_t)100096 * 4;
    float* stats   = (float*)p; p += 1024 * 4;
    u16*   wz1     = (u16*)p;   p += 16384 * 2;
    u16*   wz2     = (u16*)p;   p += 16384 * 2;

    float* sums1 = stats,       *sq1 = stats + 128;
    float* sums2 = stats + 512, *sq2 = stats + 640;

    // graph setup: histogram -> bucket bases -> partition (packed 4B) -> per-bucket
    // padded-CSR build (self folded in, zero-row pads)
    k_init<<<4, 256, 0, stream>>>(stats, (u32*)Hb + (size_t)N_NODES * 64);
    k_hist<<<PBLK, 256, 0, stream>>>(dst, hist);
    k_colscan<<<NBUCK, 256, 0, stream>>>(hist, tot);
    k_bscan<<<1, 1024, 0, stream>>>(tot, bbase);
    k_part<<<PBLK, 256, 0, stream>>>(src, dst, hist, bbase, tmp);
    k_bucket<<<NBUCK, 256, 0, stream>>>(tmp, bbase, meta, dinv, csr_src);
    k_swz<<<8, 256, 0, stream>>>(W1, wz1);
    k_swz<<<8, 256, 0, stream>>>(W2, wz2);

    // layer 1:  Hb1 = (x@W1)*dinv -> d_out (bf16),  AGG1(bf16) -> aggb
    k_gemm<false, false><<<1563, 256, 0, stream>>>(x, wz1, nullptr, nullptr, nullptr,
                                                   nullptr, dinv, Hb, N_NODES);
    k_agg<<<25000, 256, 0, stream>>>((const uint4*)Hb, meta, (const int4*)csr_src, aggb);
    k_bnstats<<<500, 256, 0, stream>>>(aggb, sums1, sq1);

    // layer 2:  Hb2 = (leaky(BN1(AGG1))@W2)*dinv -> d_out;  AGG2(bf16) -> aggb
    k_gemm<true, true><<<1563, 256, 0, stream>>>(aggb, wz2, sums1, sq1, g1, be1,
                                                 dinv, Hb, N_NODES);
    k_agg<<<25000, 256, 0, stream>>>((const uint4*)Hb, meta, (const int4*)csr_src, aggb);
    k_bnstats<<<500, 256, 0, stream>>>(aggb, sums2, sq2);

    // epilogue: BN2 finalize inline + residual + leaky
    k_ew2<<<6250, 256, 0, stream>>>((const uint4*)aggb, sums2, sq2, g2, be2,
                                    (const float4*)x, (float4*)out);
}